// Round 8
// baseline (133.878 us; speedup 1.0000x reference)
//
#include <hip/hip_runtime.h>
#include <hip/hip_bf16.h>

typedef __attribute__((ext_vector_type(8))) short short8;
typedef __attribute__((ext_vector_type(4))) float floatx4;
typedef __attribute__((ext_vector_type(4))) int intx4;

__device__ __forceinline__ unsigned short f2bf(float x) {
    union { float f; unsigned u; } v; v.f = x;
    unsigned r = v.u + 0x7fffu + ((v.u >> 16) & 1u);   // RNE; inputs here are never NaN
    return (unsigned short)(r >> 16);
}

__device__ __forceinline__ short8 pack8(float4 a, float4 b) {
    short8 s;
    s[0] = (short)f2bf(a.x); s[1] = (short)f2bf(a.y);
    s[2] = (short)f2bf(a.z); s[3] = (short)f2bf(a.w);
    s[4] = (short)f2bf(b.x); s[5] = (short)f2bf(b.y);
    s[6] = (short)f2bf(b.z); s[7] = (short)f2bf(b.w);
    return s;
}

__device__ __forceinline__ float fast_tanh(float x) {
    float e = __expf(2.0f * x);
    return 1.0f - 2.0f * __builtin_amdgcn_rcpf(e + 1.0f);
}

// ---------------------------------------------------------------------------
// Projection as MFMA GEMM (proven round-0/1 version, byte-identical).
// Output in PRE-FRAGMENTED TILE LAYOUT:
//   frag[b][stile=s/16][kchunk=ch/32][lane][8shorts], ch = h*64+e.
// ---------------------------------------------------------------------------
__global__ __launch_bounds__(256) void proj_kernel(
    const float* __restrict__ qin, const float* __restrict__ kin,
    const float* __restrict__ Wq, const float* __restrict__ bq,
    const float* __restrict__ Wk, const float* __restrict__ bk,
    const float* __restrict__ Wc,
    unsigned short* __restrict__ qt, unsigned short* __restrict__ kt)
{
    __shared__ unsigned short scr[4][16 * 72];
    const int which = blockIdx.y;             // 0 = q, 1 = k
    const float* in  = which ? kin : qin;
    const float* W   = which ? Wk  : Wq;
    const float* bi  = which ? bk  : bq;
    unsigned short* out = which ? kt : qt;

    const int tid  = threadIdx.x;
    const int lane = tid & 63;
    const int w    = tid >> 6;
    const int ln   = lane & 15;
    const int g    = lane >> 4;

    short8 wf[4][2];
    #pragma unroll
    for (int c = 0; c < 4; ++c)
        #pragma unroll
        for (int t = 0; t < 2; ++t) {
            const float* p = W + (c * 16 + ln) * 64 + t * 32 + (g << 3);
            wf[c][t] = pack8(*(const float4*)p, *(const float4*)(p + 4));
        }
    float be[4];
    #pragma unroll
    for (int c = 0; c < 4; ++c) be[c] = bi[c * 16 + ln];

    const int rb = blockIdx.x << 6;           // block's 64 rows: same (b,h)
    const int b  = rb >> 14;
    const int h  = (rb >> 10) & 15;
    const float sc = which ? 1.0f : Wc[h];

    const int r0 = rb + (w << 4);             // this wave's 16 rows (one s-tile)
    const int s0 = (rb & 1023) + (w << 4);
    floatx4 acc[4] = {{0,0,0,0},{0,0,0,0},{0,0,0,0},{0,0,0,0}};
    #pragma unroll
    for (int t = 0; t < 2; ++t) {
        const float* p = in + (size_t)(r0 + ln) * 64 + t * 32 + (g << 3);
        short8 af = pack8(*(const float4*)p, *(const float4*)(p + 4));
        #pragma unroll
        for (int c = 0; c < 4; ++c)
            acc[c] = __builtin_amdgcn_mfma_f32_16x16x32_bf16(af, wf[c][t], acc[c], 0, 0, 0);
    }

    // C/D: col e = c*16+ln, row m = g*4+r.  Stage tile (16 s x 64 e) in LDS.
    unsigned short* s_scr = scr[w];
    #pragma unroll
    for (int c = 0; c < 4; ++c)
        #pragma unroll
        for (int r = 0; r < 4; ++r)
            s_scr[((g << 2) + r) * 72 + (c << 4) + ln] =
                f2bf(fast_tanh(acc[c][r] + be[c]) * sc);
    __syncthreads();

    const int itg = (b << 6) + (s0 >> 4);
    unsigned short* obase = out + ((size_t)(itg * 32 + h * 2) << 9) + (lane << 3);
    #pragma unroll
    for (int e2 = 0; e2 < 2; ++e2) {          // kchunk = h*2 + e2
        short8 v = *(const short8*)&s_scr[ln * 72 + (e2 << 5) + (g << 3)];
        *(short8*)(obase + (e2 << 9)) = v;
    }
}

// ---------------------------------------------------------------------------
// attn, round-8: round-7 (fence-free rendezvous, 131.9 us — best measured)
// with the MASK LDS ROUND-TRIP DELETED.  The 66 KB mask tile was written
// once and read exactly once (epilogue); since the C/D fragment mapping is
// static per thread, each thread now loads its own 16 mask ints directly
// from global in fragment order at kernel start (issue-early / use-at-end,
// maximal T14 split) and keeps them in VGPRs.  Removes the mask staging
// phase (4 NT int4 loads + LDS writes before the first barrier), the 66 KB
// LDS footprint, and the epilogue LDS dependency.  Mask bytes fetched are
// unchanged (64 KB/block, 64-B-segment coalescing per 16-lane group).
// Everything else byte-identical to round-7.
// ---------------------------------------------------------------------------
#define RVMAGIC 0x9E3779B97F4A7C15ULL

__global__ __launch_bounds__(1024, 4) void attn_kernel(
    const unsigned short* __restrict__ qt, const unsigned short* __restrict__ kt,
    const int* __restrict__ mask, float* __restrict__ out,
    float* __restrict__ psums, unsigned long long* __restrict__ pflags)
{
    __shared__ __align__(16) unsigned short Al[32768];   // 64 KB: 2 s-tiles, frag order
    __shared__ float red[16][32];
    __shared__ float tot0[32], tot1[32];

    const int tid  = threadIdx.x;
    const int lane = tid & 63;
    const int w    = tid >> 6;                // 0..15
    const int ln   = lane & 15;
    const int g    = lane >> 4;

    const int id  = blockIdx.x;
    const int b   = id & 3;
    const int qlo = (id >> 2) & 1;
    const int ks  = (id >> 3) & 1;            // k-half; sibling = id ^ 8 (same XCD)
    const int qs  = ((id >> 4) << 1) | qlo;   // 0..31: 32-row q supertile
    const int i0  = qs << 5;
    const int slot = (((b << 5) + qs) << 1) + ks;
    const int sib  = slot ^ 1;

    // ---- mask: direct per-thread loads in C/D fragment order (no LDS).
    //      Issued first; consumed only in the epilogue (~whole kernel later).
    const int* mSrc = mask + ((size_t)((b << 10) + i0) << 10) + (ks << 9);
    int mfr[2][2][4];
    #pragma unroll
    for (int st = 0; st < 2; ++st)
        #pragma unroll
        for (int nt = 0; nt < 2; ++nt) {
            const int j = (w << 5) + (nt << 4) + ln;
            #pragma unroll
            for (int r = 0; r < 4; ++r) {
                const int row = (st << 4) + (g << 2) + r;
                mfr[st][nt][r] = __builtin_nontemporal_load(mSrc + (row << 10) + j);
            }
        }

    // ---- stage A: two consecutive 16-row tiles, 64 KB linear copy ----
    const unsigned short* aSrc = qt + ((size_t)((b << 6) + (qs << 1)) << 14);
    #pragma unroll
    for (int rr = 0; rr < 4; ++rr) {
        const int idx = (rr << 10) + tid;     // 8-short chunk id
        *(short8*)&Al[idx << 3] = *(const short8*)(aSrc + ((size_t)idx << 3));
    }
    __syncthreads();

    const unsigned short* bP = kt + ((size_t)((b << 6) + (ks << 5) + (w << 1)) << 14) + (lane << 3);
    const unsigned short* a0 = &Al[lane << 3];
    const unsigned short* a1 = &Al[16384 + (lane << 3)];

    floatx4 acc[2][2] = {{{0,0,0,0},{0,0,0,0}},{{0,0,0,0},{0,0,0,0}}};

    short8 av0 = *(const short8*)a0;
    short8 av1 = *(const short8*)a1;
    short8 bv0 = *(const short8*)bP;
    short8 bv1 = *(const short8*)(bP + (1 << 14));

    for (int kc = 1; kc < 32; ++kc) {
        const int o = kc << 9;                // chunk stride = 512 shorts = 1 KB
        short8 an0 = *(const short8*)(a0 + o);            // ds_read_b128
        short8 an1 = *(const short8*)(a1 + o);
        short8 bn0 = *(const short8*)(bP + o);
        short8 bn1 = *(const short8*)(bP + (1 << 14) + o);
        acc[0][0] = __builtin_amdgcn_mfma_f32_16x16x32_bf16(av0, bv0, acc[0][0], 0, 0, 0);
        acc[0][1] = __builtin_amdgcn_mfma_f32_16x16x32_bf16(av0, bv1, acc[0][1], 0, 0, 0);
        acc[1][0] = __builtin_amdgcn_mfma_f32_16x16x32_bf16(av1, bv0, acc[1][0], 0, 0, 0);
        acc[1][1] = __builtin_amdgcn_mfma_f32_16x16x32_bf16(av1, bv1, acc[1][1], 0, 0, 0);
        av0 = an0; av1 = an1; bv0 = bn0; bv1 = bn1;
    }
    acc[0][0] = __builtin_amdgcn_mfma_f32_16x16x32_bf16(av0, bv0, acc[0][0], 0, 0, 0);
    acc[0][1] = __builtin_amdgcn_mfma_f32_16x16x32_bf16(av0, bv1, acc[0][1], 0, 0, 0);
    acc[1][0] = __builtin_amdgcn_mfma_f32_16x16x32_bf16(av1, bv0, acc[1][0], 0, 0, 0);
    acc[1][1] = __builtin_amdgcn_mfma_f32_16x16x32_bf16(av1, bv1, acc[1][1], 0, 0, 0);

    // epilogue: masked exp from REGISTER mask; C/D: row = st*16 + g*4 + r,
    // col = w*32 + nt*16 + ln
    float psum[2][4] = {{0.f,0.f,0.f,0.f},{0.f,0.f,0.f,0.f}};
    #pragma unroll
    for (int st = 0; st < 2; ++st)
        #pragma unroll
        for (int nt = 0; nt < 2; ++nt) {
            #pragma unroll
            for (int r = 0; r < 4; ++r) {
                float e = mfr[st][nt][r] ? __expf(acc[st][nt][r]) : 0.0f;
                acc[st][nt][r] = e;
                psum[st][r] += e;
            }
        }
    #pragma unroll
    for (int off = 1; off < 16; off <<= 1)
        #pragma unroll
        for (int st = 0; st < 2; ++st)
            #pragma unroll
            for (int r = 0; r < 4; ++r) psum[st][r] += __shfl_xor(psum[st][r], off);
    if (ln == 0) {
        #pragma unroll
        for (int st = 0; st < 2; ++st)
            #pragma unroll
            for (int r = 0; r < 4; ++r)
                red[w][(st << 4) + (g << 2) + r] = psum[st][r];
    }
    __syncthreads();

    // block-half row sums -> publish; rendezvous with sibling (other k-half).
    // Fence-free (round-7 verified): siblings share an XCD, relaxed atomics
    // hit L2 directly, barrier drains vmcnt before the flag publishes.
    if (tid < 32) {
        float s = 0.f;
        #pragma unroll
        for (int ww = 0; ww < 16; ++ww) s += red[ww][tid];
        tot0[tid] = s;
        __hip_atomic_store(&psums[(slot << 5) + tid], s,
                           __ATOMIC_RELAXED, __HIP_MEMORY_SCOPE_AGENT);
    }
    __syncthreads();                          // vmcnt(0) drain: psums visible in L2
    if (tid == 0) {
        asm volatile("s_waitcnt vmcnt(0)" ::: "memory");   // belt-and-braces
        __hip_atomic_store(&pflags[slot], RVMAGIC,
                           __ATOMIC_RELAXED, __HIP_MEMORY_SCOPE_AGENT);
        int guard = 0;
        while (__hip_atomic_load(&pflags[sib], __ATOMIC_RELAXED,
                                 __HIP_MEMORY_SCOPE_AGENT) != RVMAGIC) {
            __builtin_amdgcn_s_sleep(8);
            if (++guard > (1 << 20)) break;   // failsafe ~50 ms: never hang
        }
    }
    __syncthreads();
    if (tid < 32)
        tot1[tid] = __hip_atomic_load(&psums[(sib << 5) + tid],
                                      __ATOMIC_RELAXED, __HIP_MEMORY_SCOPE_AGENT);
    __syncthreads();

    // normalize with combined denominators; REGULAR stores (full-line L2
    // write-back; round-5 verified no RMW amplification)
    float* ob = out + ((size_t)((b << 10) + i0) << 10) + (ks << 9);
    #pragma unroll
    for (int st = 0; st < 2; ++st) {
        #pragma unroll
        for (int r = 0; r < 4; ++r) {
            const int row = (st << 4) + (g << 2) + r;
            const float inv = 1.0f / (tot0[row] + tot1[row]);
            #pragma unroll
            for (int nt = 0; nt < 2; ++nt) {
                const int j = (w << 5) + (nt << 4) + ln;
                ob[((size_t)row << 10) + j] = acc[st][nt][r] * inv;
            }
        }
    }
}

extern "C" void kernel_launch(void* const* d_in, const int* in_sizes, int n_in,
                              void* d_out, int out_size, void* d_ws, size_t ws_size,
                              hipStream_t stream)
{
    const float* query = (const float*)d_in[0];
    const float* key   = (const float*)d_in[1];
    const int*   mask  = (const int*)d_in[2];
    const float* Wq    = (const float*)d_in[3];
    const float* bq    = (const float*)d_in[4];
    const float* Wk    = (const float*)d_in[5];
    const float* bk    = (const float*)d_in[6];
    const float* Wc    = (const float*)d_in[7];
    // d_in[8] (bc) intentionally unused: constant shift cancels in softmax.

    float* out = (float*)d_out;
    unsigned short* qt = (unsigned short*)d_ws;                 // 8 MiB bf16 (frag layout)
    unsigned short* kt = qt + (size_t)4 * 1024 * 1024;          // 8 MiB bf16 (frag layout)
    char* extra = (char*)d_ws + (size_t)16 * 1024 * 1024;
    float* psums = (float*)extra;                               // 256 slots x 32 floats
    unsigned long long* pflags = (unsigned long long*)(extra + 32 * 1024);

    proj_kernel<<<dim3(1024, 2), 256, 0, stream>>>(query, key, Wq, bq, Wk, bk, Wc, qt, kt);
    attn_kernel<<<256, 1024, 0, stream>>>(qt, kt, mask, out, psums, pflags);
}

// Round 9
// 133.365 us; speedup vs baseline: 1.0039x; 1.0039x over previous
//
#include <hip/hip_runtime.h>
#include <hip/hip_bf16.h>

typedef __attribute__((ext_vector_type(8))) short short8;
typedef __attribute__((ext_vector_type(4))) float floatx4;
typedef __attribute__((ext_vector_type(4))) int intx4;

__device__ __forceinline__ unsigned short f2bf(float x) {
    union { float f; unsigned u; } v; v.f = x;
    unsigned r = v.u + 0x7fffu + ((v.u >> 16) & 1u);   // RNE; inputs here are never NaN
    return (unsigned short)(r >> 16);
}

__device__ __forceinline__ short8 pack8(float4 a, float4 b) {
    short8 s;
    s[0] = (short)f2bf(a.x); s[1] = (short)f2bf(a.y);
    s[2] = (short)f2bf(a.z); s[3] = (short)f2bf(a.w);
    s[4] = (short)f2bf(b.x); s[5] = (short)f2bf(b.y);
    s[6] = (short)f2bf(b.z); s[7] = (short)f2bf(b.w);
    return s;
}

__device__ __forceinline__ float fast_tanh(float x) {
    float e = __expf(2.0f * x);
    return 1.0f - 2.0f * __builtin_amdgcn_rcpf(e + 1.0f);
}

// ---------------------------------------------------------------------------
// Projection as MFMA GEMM (proven round-0/1 version, byte-identical).
// Output in PRE-FRAGMENTED TILE LAYOUT:
//   frag[b][stile=s/16][kchunk=ch/32][lane][8shorts], ch = h*64+e.
// ---------------------------------------------------------------------------
__global__ __launch_bounds__(256) void proj_kernel(
    const float* __restrict__ qin, const float* __restrict__ kin,
    const float* __restrict__ Wq, const float* __restrict__ bq,
    const float* __restrict__ Wk, const float* __restrict__ bk,
    const float* __restrict__ Wc,
    unsigned short* __restrict__ qt, unsigned short* __restrict__ kt)
{
    __shared__ unsigned short scr[4][16 * 72];
    const int which = blockIdx.y;             // 0 = q, 1 = k
    const float* in  = which ? kin : qin;
    const float* W   = which ? Wk  : Wq;
    const float* bi  = which ? bk  : bq;
    unsigned short* out = which ? kt : qt;

    const int tid  = threadIdx.x;
    const int lane = tid & 63;
    const int w    = tid >> 6;
    const int ln   = lane & 15;
    const int g    = lane >> 4;

    short8 wf[4][2];
    #pragma unroll
    for (int c = 0; c < 4; ++c)
        #pragma unroll
        for (int t = 0; t < 2; ++t) {
            const float* p = W + (c * 16 + ln) * 64 + t * 32 + (g << 3);
            wf[c][t] = pack8(*(const float4*)p, *(const float4*)(p + 4));
        }
    float be[4];
    #pragma unroll
    for (int c = 0; c < 4; ++c) be[c] = bi[c * 16 + ln];

    const int rb = blockIdx.x << 6;           // block's 64 rows: same (b,h)
    const int b  = rb >> 14;
    const int h  = (rb >> 10) & 15;
    const float sc = which ? 1.0f : Wc[h];

    const int r0 = rb + (w << 4);             // this wave's 16 rows (one s-tile)
    const int s0 = (rb & 1023) + (w << 4);
    floatx4 acc[4] = {{0,0,0,0},{0,0,0,0},{0,0,0,0},{0,0,0,0}};
    #pragma unroll
    for (int t = 0; t < 2; ++t) {
        const float* p = in + (size_t)(r0 + ln) * 64 + t * 32 + (g << 3);
        short8 af = pack8(*(const float4*)p, *(const float4*)(p + 4));
        #pragma unroll
        for (int c = 0; c < 4; ++c)
            acc[c] = __builtin_amdgcn_mfma_f32_16x16x32_bf16(af, wf[c][t], acc[c], 0, 0, 0);
    }

    // C/D: col e = c*16+ln, row m = g*4+r.  Stage tile (16 s x 64 e) in LDS.
    unsigned short* s_scr = scr[w];
    #pragma unroll
    for (int c = 0; c < 4; ++c)
        #pragma unroll
        for (int r = 0; r < 4; ++r)
            s_scr[((g << 2) + r) * 72 + (c << 4) + ln] =
                f2bf(fast_tanh(acc[c][r] + be[c]) * sc);
    __syncthreads();

    const int itg = (b << 6) + (s0 >> 4);
    unsigned short* obase = out + ((size_t)(itg * 32 + h * 2) << 9) + (lane << 3);
    #pragma unroll
    for (int e2 = 0; e2 < 2; ++e2) {          // kchunk = h*2 + e2
        short8 v = *(const short8*)&s_scr[ln * 72 + (e2 << 5) + (g << 3)];
        *(short8*)(obase + (e2 << 9)) = v;
    }
}

// ---------------------------------------------------------------------------
// attn, round-9: EXACT round-7 kernel (fence-free rendezvous, 131.9 us best
// measured; round-8's mask-in-VGPR variant regressed ~2 us and is reverted)
// with ONE tweak: the K-loop's initial B loads (bv0/bv1, global, no LDS dep)
// are hoisted ABOVE the A-staging barrier so their L2 latency hides under
// the 64 KB A-copy instead of serializing after the barrier.  This isolates
// the only un-tested mechanism from round-2's bundle.
// Pre-commit: if this lands within noise of 131.9, the schedule family is
// at its practical floor and next round is the roofline statement.
// ---------------------------------------------------------------------------
#define RVMAGIC 0x9E3779B97F4A7C15ULL

__global__ __launch_bounds__(1024, 4) void attn_kernel(
    const unsigned short* __restrict__ qt, const unsigned short* __restrict__ kt,
    const int* __restrict__ mask, float* __restrict__ out,
    float* __restrict__ psums, unsigned long long* __restrict__ pflags)
{
    __shared__ __align__(16) unsigned short Al[32768];   // 64 KB: 2 s-tiles, frag order
    __shared__ __align__(16) int Ml[32 * 516];           // ~66 KB mask tile, padded rows
    __shared__ float red[16][32];
    __shared__ float tot0[32], tot1[32];

    const int tid  = threadIdx.x;
    const int lane = tid & 63;
    const int w    = tid >> 6;                // 0..15
    const int ln   = lane & 15;
    const int g    = lane >> 4;

    const int id  = blockIdx.x;
    const int b   = id & 3;
    const int qlo = (id >> 2) & 1;
    const int ks  = (id >> 3) & 1;            // k-half; sibling = id ^ 8 (same XCD)
    const int qs  = ((id >> 4) << 1) | qlo;   // 0..31: 32-row q supertile
    const int i0  = qs << 5;
    const int slot = (((b << 5) + qs) << 1) + ks;
    const int sib  = slot ^ 1;

    // ---- B prologue HOISTED: first K-chunk loads issue before A-staging,
    //      latency hides under the 64 KB LDS copy (only change vs round-7) ----
    const unsigned short* bP = kt + ((size_t)((b << 6) + (ks << 5) + (w << 1)) << 14) + (lane << 3);
    short8 bv0 = *(const short8*)bP;
    short8 bv1 = *(const short8*)(bP + (1 << 14));

    // ---- stage A: two consecutive 16-row tiles, 64 KB linear copy ----
    const unsigned short* aSrc = qt + ((size_t)((b << 6) + (qs << 1)) << 14);
    #pragma unroll
    for (int rr = 0; rr < 4; ++rr) {
        const int idx = (rr << 10) + tid;     // 8-short chunk id
        *(short8*)&Al[idx << 3] = *(const short8*)(aSrc + ((size_t)idx << 3));
    }
    // ---- stage mask: 32 rows x 512 ints (this k-half), row stride 516 ----
    const int* mSrc = mask + ((size_t)((b << 10) + i0) << 10) + (ks << 9);
    #pragma unroll
    for (int rr = 0; rr < 4; ++rr) {
        const int idx = (rr << 10) + tid;     // int4 chunk id, 128 per row
        const int li  = idx >> 7;
        const int cj  = idx & 127;
        intx4 mv = __builtin_nontemporal_load((const intx4*)(mSrc + (li << 10) + (cj << 2)));
        *(intx4*)&Ml[li * 516 + (cj << 2)] = mv;
    }
    __syncthreads();

    const unsigned short* a0 = &Al[lane << 3];
    const unsigned short* a1 = &Al[16384 + (lane << 3)];

    floatx4 acc[2][2] = {{{0,0,0,0},{0,0,0,0}},{{0,0,0,0},{0,0,0,0}}};

    short8 av0 = *(const short8*)a0;
    short8 av1 = *(const short8*)a1;

    for (int kc = 1; kc < 32; ++kc) {
        const int o = kc << 9;                // chunk stride = 512 shorts = 1 KB
        short8 an0 = *(const short8*)(a0 + o);            // ds_read_b128
        short8 an1 = *(const short8*)(a1 + o);
        short8 bn0 = *(const short8*)(bP + o);
        short8 bn1 = *(const short8*)(bP + (1 << 14) + o);
        acc[0][0] = __builtin_amdgcn_mfma_f32_16x16x32_bf16(av0, bv0, acc[0][0], 0, 0, 0);
        acc[0][1] = __builtin_amdgcn_mfma_f32_16x16x32_bf16(av0, bv1, acc[0][1], 0, 0, 0);
        acc[1][0] = __builtin_amdgcn_mfma_f32_16x16x32_bf16(av1, bv0, acc[1][0], 0, 0, 0);
        acc[1][1] = __builtin_amdgcn_mfma_f32_16x16x32_bf16(av1, bv1, acc[1][1], 0, 0, 0);
        av0 = an0; av1 = an1; bv0 = bn0; bv1 = bn1;
    }
    acc[0][0] = __builtin_amdgcn_mfma_f32_16x16x32_bf16(av0, bv0, acc[0][0], 0, 0, 0);
    acc[0][1] = __builtin_amdgcn_mfma_f32_16x16x32_bf16(av0, bv1, acc[0][1], 0, 0, 0);
    acc[1][0] = __builtin_amdgcn_mfma_f32_16x16x32_bf16(av1, bv0, acc[1][0], 0, 0, 0);
    acc[1][1] = __builtin_amdgcn_mfma_f32_16x16x32_bf16(av1, bv1, acc[1][1], 0, 0, 0);

    // epilogue: masked exp; C/D: row = st*16 + g*4 + r, col = w*32 + nt*16 + ln
    float psum[2][4] = {{0.f,0.f,0.f,0.f},{0.f,0.f,0.f,0.f}};
    #pragma unroll
    for (int st = 0; st < 2; ++st)
        #pragma unroll
        for (int nt = 0; nt < 2; ++nt) {
            const int j = (w << 5) + (nt << 4) + ln;
            #pragma unroll
            for (int r = 0; r < 4; ++r) {
                const int mv = Ml[((st << 4) + (g << 2) + r) * 516 + j];
                float e = mv ? __expf(acc[st][nt][r]) : 0.0f;
                acc[st][nt][r] = e;
                psum[st][r] += e;
            }
        }
    #pragma unroll
    for (int off = 1; off < 16; off <<= 1)
        #pragma unroll
        for (int st = 0; st < 2; ++st)
            #pragma unroll
            for (int r = 0; r < 4; ++r) psum[st][r] += __shfl_xor(psum[st][r], off);
    if (ln == 0) {
        #pragma unroll
        for (int st = 0; st < 2; ++st)
            #pragma unroll
            for (int r = 0; r < 4; ++r)
                red[w][(st << 4) + (g << 2) + r] = psum[st][r];
    }
    __syncthreads();

    // block-half row sums -> publish; rendezvous with sibling (other k-half).
    // Fence-free (round-7 verified, -5 us): siblings share an XCD, relaxed
    // atomics hit L2 directly, barrier drains vmcnt before the flag publishes.
    if (tid < 32) {
        float s = 0.f;
        #pragma unroll
        for (int ww = 0; ww < 16; ++ww) s += red[ww][tid];
        tot0[tid] = s;
        __hip_atomic_store(&psums[(slot << 5) + tid], s,
                           __ATOMIC_RELAXED, __HIP_MEMORY_SCOPE_AGENT);
    }
    __syncthreads();                          // vmcnt(0) drain: psums visible in L2
    if (tid == 0) {
        asm volatile("s_waitcnt vmcnt(0)" ::: "memory");   // belt-and-braces
        __hip_atomic_store(&pflags[slot], RVMAGIC,
                           __ATOMIC_RELAXED, __HIP_MEMORY_SCOPE_AGENT);
        int guard = 0;
        while (__hip_atomic_load(&pflags[sib], __ATOMIC_RELAXED,
                                 __HIP_MEMORY_SCOPE_AGENT) != RVMAGIC) {
            __builtin_amdgcn_s_sleep(8);
            if (++guard > (1 << 20)) break;   // failsafe ~50 ms: never hang
        }
    }
    __syncthreads();
    if (tid < 32)
        tot1[tid] = __hip_atomic_load(&psums[(sib << 5) + tid],
                                      __ATOMIC_RELAXED, __HIP_MEMORY_SCOPE_AGENT);
    __syncthreads();

    // normalize with combined denominators; REGULAR stores (full-line L2
    // write-back; round-5 verified no RMW amplification)
    float* ob = out + ((size_t)((b << 10) + i0) << 10) + (ks << 9);
    #pragma unroll
    for (int st = 0; st < 2; ++st) {
        #pragma unroll
        for (int r = 0; r < 4; ++r) {
            const int row = (st << 4) + (g << 2) + r;
            const float inv = 1.0f / (tot0[row] + tot1[row]);
            #pragma unroll
            for (int nt = 0; nt < 2; ++nt) {
                const int j = (w << 5) + (nt << 4) + ln;
                ob[((size_t)row << 10) + j] = acc[st][nt][r] * inv;
            }
        }
    }
}

extern "C" void kernel_launch(void* const* d_in, const int* in_sizes, int n_in,
                              void* d_out, int out_size, void* d_ws, size_t ws_size,
                              hipStream_t stream)
{
    const float* query = (const float*)d_in[0];
    const float* key   = (const float*)d_in[1];
    const int*   mask  = (const int*)d_in[2];
    const float* Wq    = (const float*)d_in[3];
    const float* bq    = (const float*)d_in[4];
    const float* Wk    = (const float*)d_in[5];
    const float* bk    = (const float*)d_in[6];
    const float* Wc    = (const float*)d_in[7];
    // d_in[8] (bc) intentionally unused: constant shift cancels in softmax.

    float* out = (float*)d_out;
    unsigned short* qt = (unsigned short*)d_ws;                 // 8 MiB bf16 (frag layout)
    unsigned short* kt = qt + (size_t)4 * 1024 * 1024;          // 8 MiB bf16 (frag layout)
    char* extra = (char*)d_ws + (size_t)16 * 1024 * 1024;
    float* psums = (float*)extra;                               // 256 slots x 32 floats
    unsigned long long* pflags = (unsigned long long*)(extra + 32 * 1024);

    proj_kernel<<<dim3(1024, 2), 256, 0, stream>>>(query, key, Wq, bq, Wk, bk, Wc, qt, kt);
    attn_kernel<<<256, 1024, 0, stream>>>(qt, kt, mask, out, psums, pflags);
}